// Round 1
// baseline (97.468 us; speedup 1.0000x reference)
//
#include <hip/hip_runtime.h>
#include <math.h>

#define HW 16384  // 128*128

// ---------------------------------------------------------------------------
// Kernel A: weff[b,o,c] = conv_w[o,c] * (1/sqrt(512)) * s[b,c],
//           s[b,c] = (1/sqrt(512)) * sum_j style[b,j]*mod_w[c,j] + mod_b[c]
// ---------------------------------------------------------------------------
__global__ __launch_bounds__(512) void mod_kernel(
    const float* __restrict__ style, const float* __restrict__ mod_w,
    const float* __restrict__ mod_b, const float* __restrict__ conv_w,
    float* __restrict__ weff) {
  int b = blockIdx.x;
  int i = threadIdx.x;  // channel 0..511
  __shared__ float st[512];
  st[i] = style[b * 512 + i];
  __syncthreads();
  const float4* row = reinterpret_cast<const float4*>(mod_w + (size_t)i * 512);
  float s = 0.f;
#pragma unroll 4
  for (int j = 0; j < 128; ++j) {
    float4 v = row[j];
    s += v.x * st[4 * j + 0] + v.y * st[4 * j + 1] + v.z * st[4 * j + 2] +
         v.w * st[4 * j + 3];
  }
  const float kInv = 0.04419417382415922f;  // 1/sqrt(512)
  s = s * kInv + mod_b[i];
#pragma unroll
  for (int o = 0; o < 3; ++o)
    weff[(b * 3 + o) * 512 + i] = conv_w[o * 512 + i] * kInv * s;
}

// ---------------------------------------------------------------------------
// Kernel B: attention energy + per-batch sum of squares.
// One thread per position inside a 4x4 block-column; 16 consecutive lanes
// form one column -> shfl_xor reductions for the per-column L2 norms.
// grid = B*64 blocks (16 columns per block), block = 256 threads.
// ---------------------------------------------------------------------------
__global__ __launch_bounds__(256) void att_kernel(
    const float* __restrict__ a0, const float* __restrict__ a1,
    const float* __restrict__ q_w, const float* __restrict__ q_b,
    float* __restrict__ energy, float* __restrict__ sumsq) {
  int blk = blockIdx.x;
  int b = blk >> 6;   // 64 blocks per batch
  int j = blk & 63;   // covers 16 columns
  int t = threadIdx.x;
  int colLocal = t >> 4;  // 0..15
  int pos = t & 15;       // 0..15
  int col = j * 16 + colLocal;  // 0..1023
  int by = col >> 5, bx = col & 31;
  int iy = pos >> 2, ix = pos & 3;
  int h = by * 4 + iy, w = bx * 4 + ix;

  __shared__ float qw[27];
  __shared__ float qb;
  if (t < 27) qw[t] = q_w[t];
  if (t == 27) qb = q_b[0];
  __syncthreads();

  float pq = qb, pk = qb;
#pragma unroll
  for (int ci = 0; ci < 3; ++ci) {
    const float* p0 = a0 + (size_t)(b * 3 + ci) * HW;
    const float* p1 = a1 + (size_t)(b * 3 + ci) * HW;
#pragma unroll
    for (int ky = 0; ky < 3; ++ky) {
      int hh = h + ky - 1;
      if ((unsigned)hh >= 128u) continue;
#pragma unroll
      for (int kx = 0; kx < 3; ++kx) {
        int ww = w + kx - 1;
        if ((unsigned)ww >= 128u) continue;
        float wq = qw[ci * 9 + ky * 3 + kx];
        pq = fmaf(wq, p0[hh * 128 + ww], pq);
        pk = fmaf(wq, p1[hh * 128 + ww], pk);
      }
    }
  }
  // per-column (16-lane-group) L2 norms
  float sq = pq * pq, sk = pk * pk;
#pragma unroll
  for (int m = 1; m < 16; m <<= 1) {
    sq += __shfl_xor(sq, m);
    sk += __shfl_xor(sk, m);
  }
  float qn = 1.0f / fmaxf(sqrtf(sq), 1e-12f);
  float kn = 1.0f / fmaxf(sqrtf(sk), 1e-12f);
  float e = (pq * qn) * (pk * kn);
  energy[(size_t)b * HW + h * 128 + w] = e;

  // per-batch Frobenius sumsq
  float ss = e * e;
#pragma unroll
  for (int m = 1; m < 64; m <<= 1) ss += __shfl_xor(ss, m);
  __shared__ float part[4];
  int wid = t >> 6;
  if ((t & 63) == 0) part[wid] = ss;
  __syncthreads();
  if (t == 0) atomicAdd(&sumsq[b], part[0] + part[1] + part[2] + part[3]);
}

// ---------------------------------------------------------------------------
// Kernel C: the 268MB streaming kernel.
// out[b,o,p] = (sum_c weff[b,o,c]*input[b,c,p] + bias[o]) * att
//            + skip_up[b,o,p] * (1-att)
// 1 pixel per thread; weff reads are block-uniform (-> s_loads).
// grid = B*64 blocks, block = 256 threads (8 waves/CU across 256 CUs).
// ---------------------------------------------------------------------------
__global__ __launch_bounds__(256) void main_kernel(
    const float* __restrict__ input, const float* __restrict__ weff,
    const float* __restrict__ bias, const float* __restrict__ skip,
    const float* __restrict__ upk, const float* __restrict__ energy,
    const float* __restrict__ sumsq, float* __restrict__ out) {
  int blk = blockIdx.x;
  int b = blk >> 6;
  int p = (blk & 63) * 256 + threadIdx.x;  // 0..16383

  const float* in = input + (size_t)b * 512 * HW + p;
  const float* w0 = weff + (size_t)(b * 3 + 0) * 512;
  const float* w1 = w0 + 512;
  const float* w2 = w1 + 512;

  float a0 = 0.f, a1 = 0.f, a2 = 0.f;
#pragma unroll 8
  for (int c = 0; c < 512; ++c) {
    float v = in[(size_t)c * HW];
    a0 = fmaf(w0[c], v, a0);
    a1 = fmaf(w1[c], v, a1);
    a2 = fmaf(w2[c], v, a2);
  }

  float att = energy[(size_t)b * HW + p] *
              (4.0f / fmaxf(sqrtf(sumsq[b]), 1e-12f));

  // skip 2x upsample (upfirdn2d up=2, pad=(2,2), 4x4 kernel) at (y,x)
  int y = p >> 7, x = p & 127;
  int syb = ((y + (y & 1)) >> 1) - 1;
  int sxb = ((x + (x & 1)) >> 1) - 1;
  int ky0 = y & 1, kx0 = x & 1;
  float s0 = 0.f, s1 = 0.f, s2 = 0.f;
#pragma unroll
  for (int a = 0; a < 2; ++a) {
    int sy = syb + a;
    if ((unsigned)sy >= 64u) continue;
#pragma unroll
    for (int c2 = 0; c2 < 2; ++c2) {
      int sx = sxb + c2;
      if ((unsigned)sx >= 64u) continue;
      float kv = upk[(ky0 + 2 * a) * 4 + (kx0 + 2 * c2)];
      size_t base = ((size_t)(b * 3) * 64 + sy) * 64 + sx;
      s0 = fmaf(kv, skip[base], s0);
      s1 = fmaf(kv, skip[base + 4096], s1);
      s2 = fmaf(kv, skip[base + 8192], s2);
    }
  }

  float om = 1.0f - att;
  size_t ob = (size_t)(b * 3) * HW + p;
  out[ob] = (a0 + bias[0]) * att + s0 * om;
  out[ob + HW] = (a1 + bias[1]) * att + s1 * om;
  out[ob + 2 * HW] = (a2 + bias[2]) * att + s2 * om;
}

// ---------------------------------------------------------------------------
extern "C" void kernel_launch(void* const* d_in, const int* in_sizes, int n_in,
                              void* d_out, int out_size, void* d_ws,
                              size_t ws_size, hipStream_t stream) {
  const float* input  = (const float*)d_in[0];
  const float* style  = (const float*)d_in[1];
  const float* skip   = (const float*)d_in[2];
  const float* att0   = (const float*)d_in[3];
  const float* att1   = (const float*)d_in[4];
  const float* conv_w = (const float*)d_in[5];
  const float* mod_w  = (const float*)d_in[6];
  const float* mod_b  = (const float*)d_in[7];
  const float* bias   = (const float*)d_in[8];
  const float* q_w    = (const float*)d_in[9];
  const float* q_b    = (const float*)d_in[10];
  const float* upk    = (const float*)d_in[11];

  int B = in_sizes[1] / 512;  // 8

  float* ws = (float*)d_ws;
  float* weff   = ws;              // B*3*512 = 12288 floats
  float* energy = ws + 12288;      // B*HW    = 131072 floats
  float* sumsq  = ws + 12288 + 131072;  // B floats

  hipMemsetAsync(sumsq, 0, B * sizeof(float), stream);
  mod_kernel<<<B, 512, 0, stream>>>(style, mod_w, mod_b, conv_w, weff);
  att_kernel<<<B * 64, 256, 0, stream>>>(att0, att1, q_w, q_b, energy, sumsq);
  main_kernel<<<B * 64, 256, 0, stream>>>(input, weff, bias, skip, upk,
                                          energy, sumsq, (float*)d_out);
}

// Round 2
// 56.134 us; speedup vs baseline: 1.7364x; 1.7364x over previous
//
#include <hip/hip_runtime.h>
#include <math.h>

#define HW 16384  // 128*128
#define MOD_BLOCKS 1024  // 4096 waves: one per (b, channel)

// ---------------------------------------------------------------------------
// Fused pre-kernel.
//   blocks [0, MOD_BLOCKS):  modulation -> weff4[b][c] = {w0,w1,w2,0}
//     one wave per (b,c): lane-parallel 512-dot + shfl reduce.
//   blocks [MOD_BLOCKS, MOD_BLOCKS+B*64): attention energy + per-block
//     partial sumsq (no atomics, no memset needed).
// ---------------------------------------------------------------------------
__global__ __launch_bounds__(256) void pre_kernel(
    const float* __restrict__ style, const float* __restrict__ mod_w,
    const float* __restrict__ mod_b, const float* __restrict__ conv_w,
    const float* __restrict__ a0in, const float* __restrict__ a1in,
    const float* __restrict__ q_w, const float* __restrict__ q_b,
    float4* __restrict__ weff4, float* __restrict__ energy,
    float* __restrict__ part) {
  int bid = blockIdx.x;
  int t = threadIdx.x;

  if (bid < MOD_BLOCKS) {
    // ---- modulation: wave wg handles batch b, channel i ----
    int wg = bid * 4 + (t >> 6);  // 0..4095
    int b = wg >> 9;
    int i = wg & 511;
    int lane = t & 63;
    const float4* row = reinterpret_cast<const float4*>(mod_w + (size_t)i * 512);
    const float4* st = reinterpret_cast<const float4*>(style + (size_t)b * 512);
    float4 r0 = row[lane], r1 = row[lane + 64];
    float4 s0 = st[lane], s1 = st[lane + 64];
    float s = r0.x * s0.x + r0.y * s0.y + r0.z * s0.z + r0.w * s0.w +
              r1.x * s1.x + r1.y * s1.y + r1.z * s1.z + r1.w * s1.w;
#pragma unroll
    for (int m = 1; m < 64; m <<= 1) s += __shfl_xor(s, m);
    if (lane == 0) {
      const float kInv = 0.04419417382415922f;  // 1/sqrt(512)
      s = s * kInv + mod_b[i];
      float4 o;
      o.x = conv_w[i] * kInv * s;
      o.y = conv_w[512 + i] * kInv * s;
      o.z = conv_w[1024 + i] * kInv * s;
      o.w = 0.f;
      weff4[(size_t)b * 512 + i] = o;
    }
    return;
  }

  // ---- attention energy ----
  int blk = bid - MOD_BLOCKS;  // 0 .. B*64-1
  int b = blk >> 6;
  int j = blk & 63;
  int colLocal = t >> 4;        // 0..15
  int pos = t & 15;             // 0..15
  int col = j * 16 + colLocal;  // 0..1023
  int by = col >> 5, bx = col & 31;
  int iy = pos >> 2, ix = pos & 3;
  int h = by * 4 + iy, w = bx * 4 + ix;

  __shared__ float qw[27];
  __shared__ float qb;
  if (t < 27) qw[t] = q_w[t];
  if (t == 27) qb = q_b[0];
  __syncthreads();

  float pq = qb, pk = qb;
#pragma unroll
  for (int ci = 0; ci < 3; ++ci) {
    const float* p0 = a0in + (size_t)(b * 3 + ci) * HW;
    const float* p1 = a1in + (size_t)(b * 3 + ci) * HW;
#pragma unroll
    for (int ky = 0; ky < 3; ++ky) {
      int hh = h + ky - 1;
      if ((unsigned)hh >= 128u) continue;
#pragma unroll
      for (int kx = 0; kx < 3; ++kx) {
        int ww = w + kx - 1;
        if ((unsigned)ww >= 128u) continue;
        float wq = qw[ci * 9 + ky * 3 + kx];
        pq = fmaf(wq, p0[hh * 128 + ww], pq);
        pk = fmaf(wq, p1[hh * 128 + ww], pk);
      }
    }
  }
  float sq = pq * pq, sk = pk * pk;
#pragma unroll
  for (int m = 1; m < 16; m <<= 1) {
    sq += __shfl_xor(sq, m);
    sk += __shfl_xor(sk, m);
  }
  float qn = 1.0f / fmaxf(sqrtf(sq), 1e-12f);
  float kn = 1.0f / fmaxf(sqrtf(sk), 1e-12f);
  float e = (pq * qn) * (pk * kn);
  energy[(size_t)b * HW + h * 128 + w] = e;

  float ss = e * e;
#pragma unroll
  for (int m = 1; m < 64; m <<= 1) ss += __shfl_xor(ss, m);
  __shared__ float partl[4];
  int wid = t >> 6;
  if ((t & 63) == 0) partl[wid] = ss;
  __syncthreads();
  if (t == 0) part[blk] = partl[0] + partl[1] + partl[2] + partl[3];
}

// ---------------------------------------------------------------------------
// Main streaming kernel (268 MB). 1 pixel/thread, 512 blocks x 256.
// weff staged in LDS as float4 (one ds_read_b128 broadcast per channel),
// channel loop unrolled 32 (32 x 256B wave-loads in flight).
// ---------------------------------------------------------------------------
__global__ __launch_bounds__(256) void main_kernel(
    const float* __restrict__ input, const float4* __restrict__ weff4,
    const float* __restrict__ bias, const float* __restrict__ skip,
    const float* __restrict__ upk, const float* __restrict__ energy,
    const float* __restrict__ part, float* __restrict__ out) {
  __shared__ float4 lw[512];
  __shared__ float ssq_sh;
  int t = threadIdx.x;
  int blk = blockIdx.x;
  int b = blk >> 6;

  // stage weff into LDS + reduce the 64 per-block partials for this batch
  const float4* g = weff4 + (size_t)b * 512;
  lw[t] = g[t];
  lw[t + 256] = g[t + 256];
  if (t < 64) {
    float ps = part[b * 64 + t];
#pragma unroll
    for (int m = 1; m < 64; m <<= 1) ps += __shfl_xor(ps, m);
    if (t == 0) ssq_sh = ps;
  }

  int p = (blk & 63) * 256 + t;  // pixel 0..16383

  // epilogue inputs, loaded early so latency overlaps the channel loop
  float e = energy[(size_t)b * HW + p];
  int y = p >> 7, x = p & 127;
  int syb = ((y + (y & 1)) >> 1) - 1;
  int sxb = ((x + (x & 1)) >> 1) - 1;
  int ky0 = y & 1, kx0 = x & 1;
  float s0 = 0.f, s1 = 0.f, s2 = 0.f;
#pragma unroll
  for (int a = 0; a < 2; ++a) {
    int sy = syb + a;
    if ((unsigned)sy >= 64u) continue;
#pragma unroll
    for (int c2 = 0; c2 < 2; ++c2) {
      int sx = sxb + c2;
      if ((unsigned)sx >= 64u) continue;
      float kv = upk[(ky0 + 2 * a) * 4 + (kx0 + 2 * c2)];
      size_t base = ((size_t)(b * 3) * 64 + sy) * 64 + sx;
      s0 = fmaf(kv, skip[base], s0);
      s1 = fmaf(kv, skip[base + 4096], s1);
      s2 = fmaf(kv, skip[base + 8192], s2);
    }
  }
  float bi0 = bias[0], bi1 = bias[1], bi2 = bias[2];

  __syncthreads();  // lw + ssq_sh ready

  const float* in = input + (size_t)b * 512 * HW + p;
  float a0 = 0.f, a1 = 0.f, a2 = 0.f;
  for (int c0 = 0; c0 < 512; c0 += 32) {
    float v[32];
#pragma unroll
    for (int u = 0; u < 32; ++u) v[u] = in[(size_t)(c0 + u) * HW];
#pragma unroll
    for (int u = 0; u < 32; ++u) {
      float4 w = lw[c0 + u];
      a0 = fmaf(w.x, v[u], a0);
      a1 = fmaf(w.y, v[u], a1);
      a2 = fmaf(w.z, v[u], a2);
    }
  }

  float att = e * (4.0f / fmaxf(sqrtf(ssq_sh), 1e-12f));
  float om = 1.0f - att;
  size_t ob = (size_t)(b * 3) * HW + p;
  out[ob] = (a0 + bi0) * att + s0 * om;
  out[ob + HW] = (a1 + bi1) * att + s1 * om;
  out[ob + 2 * HW] = (a2 + bi2) * att + s2 * om;
}

// ---------------------------------------------------------------------------
extern "C" void kernel_launch(void* const* d_in, const int* in_sizes, int n_in,
                              void* d_out, int out_size, void* d_ws,
                              size_t ws_size, hipStream_t stream) {
  const float* input  = (const float*)d_in[0];
  const float* style  = (const float*)d_in[1];
  const float* skip   = (const float*)d_in[2];
  const float* att0   = (const float*)d_in[3];
  const float* att1   = (const float*)d_in[4];
  const float* conv_w = (const float*)d_in[5];
  const float* mod_w  = (const float*)d_in[6];
  const float* mod_b  = (const float*)d_in[7];
  const float* bias   = (const float*)d_in[8];
  const float* q_w    = (const float*)d_in[9];
  const float* q_b    = (const float*)d_in[10];
  const float* upk    = (const float*)d_in[11];

  int B = in_sizes[1] / 512;  // 8

  float* ws = (float*)d_ws;
  float4* weff4 = (float4*)ws;                    // B*512 float4 = 16384 floats
  float* energy = ws + 16384;                     // B*HW = 131072 floats
  float* part   = ws + 16384 + 131072;            // B*64 = 512 floats

  pre_kernel<<<MOD_BLOCKS + B * 64, 256, 0, stream>>>(
      style, mod_w, mod_b, conv_w, att0, att1, q_w, q_b, weff4, energy, part);
  main_kernel<<<B * 64, 256, 0, stream>>>(input, weff4, bias, skip, upk,
                                          energy, part, (float*)d_out);
}